// Round 21
// baseline (79.275 us; speedup 1.0000x reference)
//
#include <hip/hip_runtime.h>
#include <stdint.h>

typedef float f32x4 __attribute__((ext_vector_type(4)));
typedef int   i32x4 __attribute__((ext_vector_type(4)));
typedef int   i32x8 __attribute__((ext_vector_type(8)));

// ArcFace constants (margin=0.5, scale=70)
constexpr float COS_M = 0.8775825618903728f;
constexpr float SIN_M = 0.4794255386042030f;
constexpr float MM    = 0.2397127693021015f;   // sin(pi-0.5)*0.5
constexpr float SCALE = 70.0f;
constexpr float LOG2E = 1.4426950408889634f;
constexpr float CA =  SCALE * COS_M * LOG2E;   // coeff on cos
constexpr float CB =  SCALE * SIN_M * LOG2E;   // coeff on sin
constexpr float CC = -SCALE * LOG2E;           // -70 shift, log2 domain

// skip threshold: c < 0.30 -> tt < -120.6 (log2); measured absmax 0.0625
// (threshold 0.2) across R5-R20, deterministic. Wave-uniform skip, gated
// per 4-value m-group (R20's 8-value coarse gate RAISED expected work).
constexpr float C0 = 0.30f;
constexpr int SCL1 = 0x7f7f7f7f;               // E8M0 127 = 1.0 per 32-block

constexpr int NB = 2048, NC = 100000, ND = 128;
constexpr int NCP = 102400;                    // padded classes = 128 cg x 800
// k_main: 2048 blocks = 16 rb x 128 cg, zero LDS/barriers, B fragment-major
// L2-resident, mfma_scale K=128, depth-3 prefetch. Waves split 2 row-halves
// x 2 col-halves: wave = 64 rows x 400 cols = 25 frags, 4 MFMA/frag ->
// per-frag fixed overhead halved per wave, B-frag loads/block 200 -> 100.

// scaled-K128 fragment-major dword index for dword d (0..31) of col c:
// lane l of frag n reads col 16n+(l&15), k=(l>>4)*32..+32 -> 8 consecutive
// dwords at n*512 + (l>>4)*128 + (l&15)*8.
__device__ __forceinline__ uint32_t widx(int c, int d) {
  return (uint32_t)((c >> 4) * 512 + (d >> 3) * 128 + (c & 15) * 8 + (d & 7));
}

// ---- normalize x rows -> fp8 e4m3, linear 128B/row; zero rowsum ----
__global__ void __launch_bounds__(256) k_norm_x(const float* __restrict__ x,
                                                uint32_t* __restrict__ xn32,
                                                float* __restrict__ rowsum) {
  const int wv = threadIdx.x >> 6, lane = threadIdx.x & 63;
  if (blockIdx.x < 8) rowsum[blockIdx.x * 256 + threadIdx.x] = 0.0f;
  const int row = blockIdx.x * 4 + wv;                  // 512 blocks
  const float2 v = reinterpret_cast<const float2*>(x + row * ND)[lane];
  float ss = v.x * v.x + v.y * v.y;
  #pragma unroll
  for (int off = 1; off < 64; off <<= 1) ss += __shfl_xor(ss, off, 64);
  const float sc = __builtin_amdgcn_rsqf(fmaxf(ss, 1e-24f));
  if (lane < 32) {
    const float4 f = reinterpret_cast<const float4*>(x + row * ND)[lane];
    int pk = __builtin_amdgcn_cvt_pk_fp8_f32(f.x * sc, f.y * sc, 0, false);
    pk = __builtin_amdgcn_cvt_pk_fp8_f32(f.z * sc, f.w * sc, pk, true);
    xn32[row * 32 + lane] = (uint32_t)pk;
  }
}

// ---- normalize w rows -> fp8 e4m3 in scaled-K128 fragment-major layout ----
// rows NC..NCP-1 zero-filled (cos=0 -> wave-uniform skip in k_main)
__global__ void __launch_bounds__(256) k_norm_w(const float* __restrict__ w,
                                                uint32_t* __restrict__ wn32) {
  const int wv = threadIdx.x >> 6, lane = threadIdx.x & 63;
  const int c = blockIdx.x * 4 + wv;                    // 25600 blocks
  if (c >= NC) {
    if (lane < 32) wn32[widx(c, lane)] = 0u;
    return;
  }
  const float2 v = reinterpret_cast<const float2*>(w + c * ND)[lane];
  float ss = v.x * v.x + v.y * v.y;
  #pragma unroll
  for (int off = 1; off < 64; off <<= 1) ss += __shfl_xor(ss, off, 64);
  const float sc = __builtin_amdgcn_rsqf(fmaxf(ss, 1e-24f));
  if (lane < 32) {
    const float4 f = reinterpret_cast<const float4*>(w + c * ND)[lane];
    int pk = __builtin_amdgcn_cvt_pk_fp8_f32(f.x * sc, f.y * sc, 0, false);
    pk = __builtin_amdgcn_cvt_pk_fp8_f32(f.z * sc, f.w * sc, pk, true);
    wn32[widx(c, lane)] = (uint32_t)pk;
  }
}

// ---- target-column cosines: exact f32 (for logit_t) + fp8-replica (for swap) ----
__global__ void __launch_bounds__(256) k_tdot(const float* __restrict__ x,
                                              const float* __restrict__ w,
                                              const uint32_t* __restrict__ xn32,
                                              const uint32_t* __restrict__ wn32,
                                              const int* __restrict__ tgt,
                                              float2* __restrict__ cost) {
  const int wv = threadIdx.x >> 6, lane = threadIdx.x & 63;
  const int b = blockIdx.x * 4 + wv;                    // 512 blocks
  const int t = tgt[b];
  const float2 xv = reinterpret_cast<const float2*>(x + b * ND)[lane];
  const float2 wv2 = reinterpret_cast<const float2*>(w + t * ND)[lane];
  float dot = xv.x * wv2.x + xv.y * wv2.y;
  float ssx = xv.x * xv.x + xv.y * xv.y;
  float ssw = wv2.x * wv2.x + wv2.y * wv2.y;
  float dq = 0.0f;
  if (lane < 32) {
    const uint32_t xa = xn32[b * 32 + lane];
    const uint32_t wa = wn32[widx(t, lane)];
    dq += __builtin_amdgcn_cvt_f32_fp8(xa, 0) * __builtin_amdgcn_cvt_f32_fp8(wa, 0);
    dq += __builtin_amdgcn_cvt_f32_fp8(xa, 1) * __builtin_amdgcn_cvt_f32_fp8(wa, 1);
    dq += __builtin_amdgcn_cvt_f32_fp8(xa, 2) * __builtin_amdgcn_cvt_f32_fp8(wa, 2);
    dq += __builtin_amdgcn_cvt_f32_fp8(xa, 3) * __builtin_amdgcn_cvt_f32_fp8(wa, 3);
  }
  #pragma unroll
  for (int off = 1; off < 64; off <<= 1) {
    dot += __shfl_xor(dot, off, 64);
    ssx += __shfl_xor(ssx, off, 64);
    ssw += __shfl_xor(ssw, off, 64);
    dq  += __shfl_xor(dq,  off, 64);
  }
  if (lane == 0) {
    const float de = dot / (sqrtf(ssx) * sqrtf(ssw));
    cost[b] = make_float2(de, dq);
  }
}

// ---- main fused GEMM (MX-scaled fp8 K=128, global->VGPR B, no LDS/barriers) ----
__global__ void __launch_bounds__(256, 4) k_main(const uint32_t* __restrict__ xn32,
                                                 const uint32_t* __restrict__ wn32,
                                                 float* __restrict__ rowsum) {
  const int wv = threadIdx.x >> 6, lane = threadIdx.x & 63;
  const int q = lane >> 4, r = lane & 15;
  // XCD-affine: xcd = b&7 owns cgs [16*xcd, 16*xcd+16)  (1.6MB/XCD L2-resident)
  const int xcd = blockIdx.x & 7, idx = blockIdx.x >> 3;  // idx 0..255
  const int cg = xcd * 16 + (idx >> 4);                 // 0..127
  const int rb = idx & 15;                              // 0..15
  const int rowbase = rb * 128 + (wv >> 1) * 64;        // row-half per wave pair
  const int fragbase = cg * 50 + (wv & 1) * 25;         // col-half per wave

  // A fragments: m=4 x (16 rows); lane holds row=rowbase+16m+r, k=q*32..+32
  i32x8 afrag[4];
  #pragma unroll
  for (int m = 0; m < 4; ++m)
    afrag[m] = *reinterpret_cast<const i32x8*>(
        xn32 + (size_t)(rowbase + 16 * m + r) * 32 + q * 8);

  float rsum[4][4] = {{0.f,0.f,0.f,0.f},{0.f,0.f,0.f,0.f},
                      {0.f,0.f,0.f,0.f},{0.f,0.f,0.f,0.f}};

  auto loadB = [&](i32x8* buf, int nn) {
    *buf = *reinterpret_cast<const i32x8*>(
        wn32 + (size_t)(fragbase + nn) * 512 + q * 128 + r * 8);
  };
  auto compute = [&](const i32x8& buf) {
    f32x4 acc[4] = {};
    __builtin_amdgcn_s_setprio(1);
    #pragma unroll
    for (int m = 0; m < 4; ++m)
      acc[m] = __builtin_amdgcn_mfma_scale_f32_16x16x128_f8f6f4(
          afrag[m], buf, acc[m], 0 /*A=fp8*/, 0 /*B=fp8*/,
          0, SCL1, 0, SCL1);
    __builtin_amdgcn_s_setprio(0);
    // per-m 4-value gate (R19-proven fire-rate x work point)
    #pragma unroll
    for (int m = 0; m < 4; ++m) {
      const float mx = fmaxf(fmaxf(acc[m][0], acc[m][1]),
                             fmaxf(acc[m][2], acc[m][3]));
      if (__any(mx > C0)) {
        #pragma unroll
        for (int e = 0; e < 4; ++e) {
          const float c = acc[m][e];
          const float s2 = fmaxf(fmaf(-c, c, 1.0f), 0.0f);
          const float sn = __builtin_amdgcn_sqrtf(s2);
          float tt = fmaf(c, CA, CC);
          tt = fmaf(sn, -CB, tt);
          rsum[m][e] += __builtin_amdgcn_exp2f(tt);
        }
      }
    }
  };

  // depth-3 prefetch pipeline, 4 named buffers (no runtime indexing); 25 frags
  i32x8 b0, b1, b2, b3;
  loadB(&b0, 0);
  loadB(&b1, 1);
  loadB(&b2, 2);
  for (int nn = 0; nn < 24; nn += 4) {
    loadB(&b3, nn + 3);                   compute(b0);
    if (nn + 4 < 25) loadB(&b0, nn + 4);  compute(b1);
    if (nn + 5 < 25) loadB(&b1, nn + 5);  compute(b2);
    if (nn + 6 < 25) loadB(&b2, nn + 6);  compute(b3);
  }
  compute(b0);                            // frag 24

  // reduce over the 16 class-lanes, then one atomic per row
  #pragma unroll
  for (int m = 0; m < 4; ++m)
    #pragma unroll
    for (int e = 0; e < 4; ++e) {
      float v = rsum[m][e];
      #pragma unroll
      for (int off = 1; off < 16; off <<= 1) v += __shfl_xor(v, off, 64);
      if (r == 0)
        atomicAdd(&rowsum[rowbase + 16 * m + 4 * q + e], v);
    }
}

// ---- finalize: target-term swap, log, mean ----
__global__ void __launch_bounds__(256) k_final(const float* __restrict__ rowsum,
                                               const float2* __restrict__ cost,
                                               float* __restrict__ out) {
  __shared__ float red[256];
  float part = 0.f;
  for (int b = threadIdx.x; b < NB; b += 256) {
    const float2 cb = cost[b];
    const float ce = fminf(cb.x, 1.0f);                       // exact cos (clip)
    const float cq = cb.y;                                    // fp8-replica cos
    const float s2 = fmaxf(fmaf(-cq, cq, 1.0f), 0.0f);
    const float sn = __builtin_amdgcn_sqrtf(s2);
    float tt = fmaf(cq, CA, CC);
    tt = fmaf(sn, -CB, tt);
    // k_main's add for the target column: fires iff its m-group max > C0;
    // group-max >= cq, and when cq <= C0 the term is <=5e-37 (negligible
    // vs rowsum ~2^-105), so replicating with (cq > C0) matches.
    const float v_ctm = (cq > C0) ? __builtin_amdgcn_exp2f(tt) : 0.0f;
    const float logit_t = SCALE * (ce - MM);                  // true target logit
    const float v_tgt = __builtin_amdgcn_exp2f((logit_t - SCALE) * LOG2E);
    float sum = rowsum[b] - v_ctm + v_tgt;
    sum = fmaxf(sum, 1e-37f);
    part += __builtin_amdgcn_logf(sum) * 0.6931471805599453f + SCALE - logit_t;
  }
  red[threadIdx.x] = part;
  __syncthreads();
  #pragma unroll
  for (int s = 128; s > 0; s >>= 1) {
    if (threadIdx.x < s) red[threadIdx.x] += red[threadIdx.x + s];
    __syncthreads();
  }
  if (threadIdx.x == 0) out[0] = red[0] * (1.0f / NB);
}

extern "C" void kernel_launch(void* const* d_in, const int* in_sizes, int n_in,
                              void* d_out, int out_size, void* d_ws, size_t ws_size,
                              hipStream_t stream) {
  const float* x   = (const float*)d_in[0];
  const int*   tgt = (const int*)d_in[1];
  const float* w   = (const float*)d_in[2];
  float* out = (float*)d_out;

  char* ws = (char*)d_ws;
  const size_t WN_B = (size_t)NCP * 128;       // 13,107,200
  const size_t XN_B = (size_t)NB * 128;        // 262,144
  uint32_t* wn32   = (uint32_t*)ws;
  uint32_t* xn32   = (uint32_t*)(ws + WN_B);
  float2*   cost   = (float2*)(ws + WN_B + XN_B);
  float*    rowsum = (float*)(ws + WN_B + XN_B + NB * 8);
  if (ws_size < WN_B + XN_B + (size_t)NB * 12) return;

  k_norm_x<<<512,   256, 0, stream>>>(x, xn32, rowsum);
  k_norm_w<<<25600, 256, 0, stream>>>(w, wn32);
  k_tdot <<<512,   256, 0, stream>>>(x, w, xn32, wn32, tgt, cost);
  k_main <<<2048,  256, 0, stream>>>(xn32, wn32, rowsum);
  k_final<<<1,     256, 0, stream>>>(rowsum, cost, out);
}

// Round 22
// 65.196 us; speedup vs baseline: 1.2160x; 1.2160x over previous
//
#include <hip/hip_runtime.h>
#include <stdint.h>

typedef float f32x4 __attribute__((ext_vector_type(4)));
typedef int   i32x8 __attribute__((ext_vector_type(8)));

// ArcFace constants (margin=0.5, scale=70)
constexpr float COS_M = 0.8775825618903728f;
constexpr float SIN_M = 0.4794255386042030f;
constexpr float MM    = 0.2397127693021015f;   // sin(pi-0.5)*0.5
constexpr float SCALE = 70.0f;
constexpr float LOG2E = 1.4426950408889634f;
constexpr float CA =  SCALE * COS_M * LOG2E;   // coeff on cos
constexpr float CB =  SCALE * SIN_M * LOG2E;   // coeff on sin
constexpr float CC = -SCALE * LOG2E;           // -70 shift, log2 domain

// skip threshold: c < 0.30 -> tt < -120.6 (log2); measured absmax 0.0625
// (threshold 0.2) across R5-R21, deterministic. Per-m 4-value gate
// (R19-proven fire-rate x work point; R20 coarse / R21 m=4 both regressed).
constexpr float C0 = 0.30f;
constexpr int SCL1 = 0x7f7f7f7f;               // E8M0 127 = 1.0 per 32-block

constexpr int NB = 2048, NC = 100000, ND = 128;
constexpr int NCP = 102400;                    // padded classes = 128 cg x 800
// k_main: R19 structure (2048 blocks = 16 rb x 128 cg, 8 waves/SIMD, zero
// LDS/barriers, B fragment-major L2-resident, mfma_scale K=128, depth-3
// B-prefetch) + T15 epilogue double-pipeline: two named acc sets so frag
// f's gate+epilogue runs under frag f+1's MFMA (kills MFMA->VALU stall).

// scaled-K128 fragment-major dword index for dword d (0..31) of class-col c
__device__ __forceinline__ uint32_t widx(int c, int d) {
  return (uint32_t)((c >> 4) * 512 + (d >> 3) * 128 + (c & 15) * 8 + (d & 7));
}

// ---- fused normalize: blocks [0,25600) do w rows, [25600,26112) do x rows ----
__global__ void __launch_bounds__(256) k_norm(const float* __restrict__ x,
                                              const float* __restrict__ w,
                                              uint32_t* __restrict__ xn32,
                                              uint32_t* __restrict__ wn32,
                                              float* __restrict__ rowsum) {
  const int wv = threadIdx.x >> 6, lane = threadIdx.x & 63;
  if (blockIdx.x < 25600) {
    const int c = blockIdx.x * 4 + wv;
    if (c >= NC) {
      if (lane < 32) wn32[widx(c, lane)] = 0u;
      return;
    }
    const float2 v = reinterpret_cast<const float2*>(w + c * ND)[lane];
    float ss = v.x * v.x + v.y * v.y;
    #pragma unroll
    for (int off = 1; off < 64; off <<= 1) ss += __shfl_xor(ss, off, 64);
    const float sc = __builtin_amdgcn_rsqf(fmaxf(ss, 1e-24f));
    if (lane < 32) {
      const float4 f = reinterpret_cast<const float4*>(w + c * ND)[lane];
      int pk = __builtin_amdgcn_cvt_pk_fp8_f32(f.x * sc, f.y * sc, 0, false);
      pk = __builtin_amdgcn_cvt_pk_fp8_f32(f.z * sc, f.w * sc, pk, true);
      wn32[widx(c, lane)] = (uint32_t)pk;
    }
  } else {
    const int bx = blockIdx.x - 25600;                  // 0..511
    if (bx < 8) rowsum[bx * 256 + threadIdx.x] = 0.0f;
    const int row = bx * 4 + wv;
    const float2 v = reinterpret_cast<const float2*>(x + row * ND)[lane];
    float ss = v.x * v.x + v.y * v.y;
    #pragma unroll
    for (int off = 1; off < 64; off <<= 1) ss += __shfl_xor(ss, off, 64);
    const float sc = __builtin_amdgcn_rsqf(fmaxf(ss, 1e-24f));
    if (lane < 32) {
      const float4 f = reinterpret_cast<const float4*>(x + row * ND)[lane];
      int pk = __builtin_amdgcn_cvt_pk_fp8_f32(f.x * sc, f.y * sc, 0, false);
      pk = __builtin_amdgcn_cvt_pk_fp8_f32(f.z * sc, f.w * sc, pk, true);
      xn32[row * 32 + lane] = (uint32_t)pk;
    }
  }
}

// ---- target-column cosines: exact f32 (for logit_t) + fp8-replica (for swap) ----
__global__ void __launch_bounds__(256) k_tdot(const float* __restrict__ x,
                                              const float* __restrict__ w,
                                              const uint32_t* __restrict__ xn32,
                                              const uint32_t* __restrict__ wn32,
                                              const int* __restrict__ tgt,
                                              float2* __restrict__ cost) {
  const int wv = threadIdx.x >> 6, lane = threadIdx.x & 63;
  const int b = blockIdx.x * 4 + wv;                    // 512 blocks
  const int t = tgt[b];
  const float2 xv = reinterpret_cast<const float2*>(x + b * ND)[lane];
  const float2 wv2 = reinterpret_cast<const float2*>(w + t * ND)[lane];
  float dot = xv.x * wv2.x + xv.y * wv2.y;
  float ssx = xv.x * xv.x + xv.y * xv.y;
  float ssw = wv2.x * wv2.x + wv2.y * wv2.y;
  float dq = 0.0f;
  if (lane < 32) {
    const uint32_t xa = xn32[b * 32 + lane];
    const uint32_t wa = wn32[widx(t, lane)];
    dq += __builtin_amdgcn_cvt_f32_fp8(xa, 0) * __builtin_amdgcn_cvt_f32_fp8(wa, 0);
    dq += __builtin_amdgcn_cvt_f32_fp8(xa, 1) * __builtin_amdgcn_cvt_f32_fp8(wa, 1);
    dq += __builtin_amdgcn_cvt_f32_fp8(xa, 2) * __builtin_amdgcn_cvt_f32_fp8(wa, 2);
    dq += __builtin_amdgcn_cvt_f32_fp8(xa, 3) * __builtin_amdgcn_cvt_f32_fp8(wa, 3);
  }
  #pragma unroll
  for (int off = 1; off < 64; off <<= 1) {
    dot += __shfl_xor(dot, off, 64);
    ssx += __shfl_xor(ssx, off, 64);
    ssw += __shfl_xor(ssw, off, 64);
    dq  += __shfl_xor(dq,  off, 64);
  }
  if (lane == 0) {
    const float de = dot / (sqrtf(ssx) * sqrtf(ssw));
    cost[b] = make_float2(de, dq);
  }
}

// ---- main fused GEMM (MX-scaled fp8 K=128, global->VGPR B, no LDS/barriers) ----
__global__ void __launch_bounds__(256, 4) k_main(const uint32_t* __restrict__ xn32,
                                                 const uint32_t* __restrict__ wn32,
                                                 float* __restrict__ rowsum) {
  const int wv = threadIdx.x >> 6, lane = threadIdx.x & 63;
  const int q = lane >> 4, r = lane & 15;
  // XCD-affine: xcd = b&7 owns cgs [16*xcd, 16*xcd+16)  (1.6MB/XCD L2-resident)
  const int xcd = blockIdx.x & 7, idx = blockIdx.x >> 3;  // idx 0..255
  const int cg = xcd * 16 + (idx >> 4);                 // 0..127
  const int rb = idx & 15;                              // 0..15
  const int rowbase = rb * 128 + wv * 32;
  const int fragbase = cg * 50;                         // 50 16-col frags per cg

  // A fragments: m=2 x (16 rows); direct i32x8 deref -> 2x dwordx4, no movs
  i32x8 afrag[2];
  #pragma unroll
  for (int m = 0; m < 2; ++m)
    afrag[m] = *reinterpret_cast<const i32x8*>(
        xn32 + (size_t)(rowbase + 16 * m + r) * 32 + q * 8);

  float rsum[2][4] = {{0.f,0.f,0.f,0.f},{0.f,0.f,0.f,0.f}};

  auto loadB = [&](i32x8* buf, int nn) {
    *buf = *reinterpret_cast<const i32x8*>(
        wn32 + (size_t)(fragbase + nn) * 512 + q * 128 + r * 8);
  };
  auto mfmaStep = [&](const i32x8& buf, f32x4* acc) {
    __builtin_amdgcn_s_setprio(1);
    #pragma unroll
    for (int m = 0; m < 2; ++m)
      acc[m] = __builtin_amdgcn_mfma_scale_f32_16x16x128_f8f6f4(
          afrag[m], buf, (f32x4){0.f, 0.f, 0.f, 0.f},
          0 /*A=fp8*/, 0 /*B=fp8*/, 0, SCL1, 0, SCL1);
    __builtin_amdgcn_s_setprio(0);
  };
  auto epi = [&](const f32x4* acc) {
    #pragma unroll
    for (int m = 0; m < 2; ++m) {
      const float mx = fmaxf(fmaxf(acc[m][0], acc[m][1]),
                             fmaxf(acc[m][2], acc[m][3]));
      if (__any(mx > C0)) {
        #pragma unroll
        for (int e = 0; e < 4; ++e) {
          const float c = acc[m][e];
          const float s2 = fmaxf(fmaf(-c, c, 1.0f), 0.0f);
          const float sn = __builtin_amdgcn_sqrtf(s2);
          float tt = fmaf(c, CA, CC);
          tt = fmaf(sn, -CB, tt);
          rsum[m][e] += __builtin_amdgcn_exp2f(tt);
        }
      }
    }
  };

  // depth-3 B-prefetch (4 named buffers) + epilogue double-pipeline
  // (2 named acc sets). Invariant at loop top: aA = mfma(frag nn),
  // b1 = frag nn+1, b2 = frag nn+2, b3 about to load frag nn+3.
  i32x8 b0, b1, b2, b3;
  f32x4 aA[2], aB[2];
  loadB(&b0, 0);
  loadB(&b1, 1);
  loadB(&b2, 2);
  mfmaStep(b0, aA);
  for (int nn = 0; nn < 48; nn += 4) {
    loadB(&b3, nn + 3);                   mfmaStep(b1, aB);  epi(aA);  // frag nn
    if (nn + 4 < 50) loadB(&b0, nn + 4);  mfmaStep(b2, aA);  epi(aB);  // frag nn+1
    if (nn + 5 < 50) loadB(&b1, nn + 5);  mfmaStep(b3, aB);  epi(aA);  // frag nn+2
    if (nn + 6 < 50) loadB(&b2, nn + 6);  mfmaStep(b0, aA);  epi(aB);  // frag nn+3
    // NOTE: line 4 writes aA AFTER epi(aA) of frag nn+2 has consumed it.
  }
  // exit state: aA = mfma(frag 48), b1 = frag 49
  mfmaStep(b1, aB);
  epi(aA);                                // frag 48
  epi(aB);                                // frag 49

  // reduce over the 16 class-lanes, then one atomic per row
  #pragma unroll
  for (int m = 0; m < 2; ++m)
    #pragma unroll
    for (int e = 0; e < 4; ++e) {
      float v = rsum[m][e];
      #pragma unroll
      for (int off = 1; off < 16; off <<= 1) v += __shfl_xor(v, off, 64);
      if (r == 0)
        atomicAdd(&rowsum[rowbase + 16 * m + 4 * q + e], v);
    }
}

// ---- finalize: target-term swap, log, mean ----
__global__ void __launch_bounds__(256) k_final(const float* __restrict__ rowsum,
                                               const float2* __restrict__ cost,
                                               float* __restrict__ out) {
  __shared__ float red[256];
  float part = 0.f;
  for (int b = threadIdx.x; b < NB; b += 256) {
    const float2 cb = cost[b];
    const float ce = fminf(cb.x, 1.0f);                       // exact cos (clip)
    const float cq = cb.y;                                    // fp8-replica cos
    const float s2 = fmaxf(fmaf(-cq, cq, 1.0f), 0.0f);
    const float sn = __builtin_amdgcn_sqrtf(s2);
    float tt = fmaf(cq, CA, CC);
    tt = fmaf(sn, -CB, tt);
    // k_main's add for the target column: fires iff its m-group max > C0;
    // group-max >= cq, and when cq <= C0 the term is <=5e-37 (negligible
    // vs rowsum ~2^-105), so replicating with (cq > C0) matches.
    const float v_ctm = (cq > C0) ? __builtin_amdgcn_exp2f(tt) : 0.0f;
    const float logit_t = SCALE * (ce - MM);                  // true target logit
    const float v_tgt = __builtin_amdgcn_exp2f((logit_t - SCALE) * LOG2E);
    float sum = rowsum[b] - v_ctm + v_tgt;
    sum = fmaxf(sum, 1e-37f);
    part += __builtin_amdgcn_logf(sum) * 0.6931471805599453f + SCALE - logit_t;
  }
  red[threadIdx.x] = part;
  __syncthreads();
  #pragma unroll
  for (int s = 128; s > 0; s >>= 1) {
    if (threadIdx.x < s) red[threadIdx.x] += red[threadIdx.x + s];
    __syncthreads();
  }
  if (threadIdx.x == 0) out[0] = red[0] * (1.0f / NB);
}

extern "C" void kernel_launch(void* const* d_in, const int* in_sizes, int n_in,
                              void* d_out, int out_size, void* d_ws, size_t ws_size,
                              hipStream_t stream) {
  const float* x   = (const float*)d_in[0];
  const int*   tgt = (const int*)d_in[1];
  const float* w   = (const float*)d_in[2];
  float* out = (float*)d_out;

  char* ws = (char*)d_ws;
  const size_t WN_B = (size_t)NCP * 128;       // 13,107,200
  const size_t XN_B = (size_t)NB * 128;        // 262,144
  uint32_t* wn32   = (uint32_t*)ws;
  uint32_t* xn32   = (uint32_t*)(ws + WN_B);
  float2*   cost   = (float2*)(ws + WN_B + XN_B);
  float*    rowsum = (float*)(ws + WN_B + XN_B + NB * 8);
  if (ws_size < WN_B + XN_B + (size_t)NB * 12) return;

  k_norm <<<26112, 256, 0, stream>>>(x, w, xn32, wn32, rowsum);
  k_tdot <<<512,   256, 0, stream>>>(x, w, xn32, wn32, tgt, cost);
  k_main <<<2048,  256, 0, stream>>>(xn32, wn32, rowsum);
  k_final<<<1,     256, 0, stream>>>(rowsum, cost, out);
}

// Round 23
// 60.004 us; speedup vs baseline: 1.3212x; 1.0865x over previous
//
#include <hip/hip_runtime.h>
#include <stdint.h>

typedef float f32x4 __attribute__((ext_vector_type(4)));
typedef int   i32x8 __attribute__((ext_vector_type(8)));

// ArcFace constants (margin=0.5, scale=70)
constexpr float COS_M = 0.8775825618903728f;
constexpr float SIN_M = 0.4794255386042030f;
constexpr float MM    = 0.2397127693021015f;   // sin(pi-0.5)*0.5
constexpr float SCALE = 70.0f;
constexpr float LOG2E = 1.4426950408889634f;
constexpr float CA =  SCALE * COS_M * LOG2E;   // coeff on cos
constexpr float CB =  SCALE * SIN_M * LOG2E;   // coeff on sin
constexpr float CC = -SCALE * LOG2E;           // -70 shift, log2 domain

// skip threshold: c < 0.30 -> tt < -120.6 (log2); measured absmax 0.0625
// (threshold 0.2) across R5-R22, deterministic. Per-m 4-value gate.
constexpr float C0 = 0.30f;
constexpr int SCL1 = 0x7f7f7f7f;               // E8M0 127 = 1.0 per 32-block

constexpr int NB = 2048, NC = 100000, ND = 128;
constexpr int NCP = 102400;                    // padded classes = 128 cg x 800
// k_main: R19/R22 structure (2048 blocks = 16 rb x 128 cg, 8 waves/SIMD,
// zero LDS/barriers, B fragment-major L2-resident, mfma_scale K=128,
// depth-3 B-prefetch, T15 acc double-pipeline). k_norm restructured:
// single float4 read per row (was double-read), 2 rows/wave, half grid.

// scaled-K128 fragment-major dword index for dword d (0..31) of class-col c
__device__ __forceinline__ uint32_t widx(int c, int d) {
  return (uint32_t)((c >> 4) * 512 + (d >> 3) * 128 + (c & 15) * 8 + (d & 7));
}

// ---- fused normalize: blocks [0,12800) w rows (8/block), [12800,13056) x ----
// Half-wave owns a row: 32 lanes x float4 = 512B single coalesced read.
__global__ void __launch_bounds__(256) k_norm(const float* __restrict__ x,
                                              const float* __restrict__ w,
                                              uint32_t* __restrict__ xn32,
                                              uint32_t* __restrict__ wn32,
                                              float* __restrict__ rowsum) {
  const int wv = threadIdx.x >> 6, lane = threadIdx.x & 63;
  const int h = lane >> 5, j = lane & 31;
  if (blockIdx.x < 12800) {
    const int c = blockIdx.x * 8 + wv * 2 + h;
    if (c >= NC) { wn32[widx(c, j)] = 0u; return; }
    const float4 f = reinterpret_cast<const float4*>(w + (size_t)c * ND)[j];
    float ss = f.x * f.x + f.y * f.y + f.z * f.z + f.w * f.w;
    #pragma unroll
    for (int off = 1; off < 32; off <<= 1) ss += __shfl_xor(ss, off, 64);
    const float sc = __builtin_amdgcn_rsqf(fmaxf(ss, 1e-24f));
    int pk = __builtin_amdgcn_cvt_pk_fp8_f32(f.x * sc, f.y * sc, 0, false);
    pk = __builtin_amdgcn_cvt_pk_fp8_f32(f.z * sc, f.w * sc, pk, true);
    wn32[widx(c, j)] = (uint32_t)pk;
  } else {
    const int bx = blockIdx.x - 12800;                  // 0..255
    if (bx < 8) rowsum[bx * 256 + threadIdx.x] = 0.0f;
    const int row = bx * 8 + wv * 2 + h;
    const float4 f = reinterpret_cast<const float4*>(x + (size_t)row * ND)[j];
    float ss = f.x * f.x + f.y * f.y + f.z * f.z + f.w * f.w;
    #pragma unroll
    for (int off = 1; off < 32; off <<= 1) ss += __shfl_xor(ss, off, 64);
    const float sc = __builtin_amdgcn_rsqf(fmaxf(ss, 1e-24f));
    int pk = __builtin_amdgcn_cvt_pk_fp8_f32(f.x * sc, f.y * sc, 0, false);
    pk = __builtin_amdgcn_cvt_pk_fp8_f32(f.z * sc, f.w * sc, pk, true);
    xn32[row * 32 + j] = (uint32_t)pk;
  }
}

// ---- target-column cosines: exact f32 (for logit_t) + fp8-replica (for swap) ----
__global__ void __launch_bounds__(256) k_tdot(const float* __restrict__ x,
                                              const float* __restrict__ w,
                                              const uint32_t* __restrict__ xn32,
                                              const uint32_t* __restrict__ wn32,
                                              const int* __restrict__ tgt,
                                              float2* __restrict__ cost) {
  const int wv = threadIdx.x >> 6, lane = threadIdx.x & 63;
  const int b = blockIdx.x * 4 + wv;                    // 512 blocks
  const int t = tgt[b];
  const float2 xv = reinterpret_cast<const float2*>(x + b * ND)[lane];
  const float2 wv2 = reinterpret_cast<const float2*>(w + t * ND)[lane];
  float dot = xv.x * wv2.x + xv.y * wv2.y;
  float ssx = xv.x * xv.x + xv.y * xv.y;
  float ssw = wv2.x * wv2.x + wv2.y * wv2.y;
  float dq = 0.0f;
  if (lane < 32) {
    const uint32_t xa = xn32[b * 32 + lane];
    const uint32_t wa = wn32[widx(t, lane)];
    dq += __builtin_amdgcn_cvt_f32_fp8(xa, 0) * __builtin_amdgcn_cvt_f32_fp8(wa, 0);
    dq += __builtin_amdgcn_cvt_f32_fp8(xa, 1) * __builtin_amdgcn_cvt_f32_fp8(wa, 1);
    dq += __builtin_amdgcn_cvt_f32_fp8(xa, 2) * __builtin_amdgcn_cvt_f32_fp8(wa, 2);
    dq += __builtin_amdgcn_cvt_f32_fp8(xa, 3) * __builtin_amdgcn_cvt_f32_fp8(wa, 3);
  }
  #pragma unroll
  for (int off = 1; off < 64; off <<= 1) {
    dot += __shfl_xor(dot, off, 64);
    ssx += __shfl_xor(ssx, off, 64);
    ssw += __shfl_xor(ssw, off, 64);
    dq  += __shfl_xor(dq,  off, 64);
  }
  if (lane == 0) {
    const float de = dot / (sqrtf(ssx) * sqrtf(ssw));
    cost[b] = make_float2(de, dq);
  }
}

// ---- main fused GEMM (MX-scaled fp8 K=128, global->VGPR B, no LDS/barriers) ----
__global__ void __launch_bounds__(256, 4) k_main(const uint32_t* __restrict__ xn32,
                                                 const uint32_t* __restrict__ wn32,
                                                 float* __restrict__ rowsum) {
  const int wv = threadIdx.x >> 6, lane = threadIdx.x & 63;
  const int q = lane >> 4, r = lane & 15;
  // XCD-affine: xcd = b&7 owns cgs [16*xcd, 16*xcd+16)  (1.6MB/XCD L2-resident)
  const int xcd = blockIdx.x & 7, idx = blockIdx.x >> 3;  // idx 0..255
  const int cg = xcd * 16 + (idx >> 4);                 // 0..127
  const int rb = idx & 15;                              // 0..15
  const int rowbase = rb * 128 + wv * 32;
  const int fragbase = cg * 50;                         // 50 16-col frags per cg

  // A fragments: m=2 x (16 rows); direct i32x8 deref -> 2x dwordx4, no movs
  i32x8 afrag[2];
  #pragma unroll
  for (int m = 0; m < 2; ++m)
    afrag[m] = *reinterpret_cast<const i32x8*>(
        xn32 + (size_t)(rowbase + 16 * m + r) * 32 + q * 8);

  float rsum[2][4] = {{0.f,0.f,0.f,0.f},{0.f,0.f,0.f,0.f}};

  auto loadB = [&](i32x8* buf, int nn) {
    *buf = *reinterpret_cast<const i32x8*>(
        wn32 + (size_t)(fragbase + nn) * 512 + q * 128 + r * 8);
  };
  auto mfmaStep = [&](const i32x8& buf, f32x4* acc) {
    __builtin_amdgcn_s_setprio(1);
    #pragma unroll
    for (int m = 0; m < 2; ++m)
      acc[m] = __builtin_amdgcn_mfma_scale_f32_16x16x128_f8f6f4(
          afrag[m], buf, (f32x4){0.f, 0.f, 0.f, 0.f},
          0 /*A=fp8*/, 0 /*B=fp8*/, 0, SCL1, 0, SCL1);
    __builtin_amdgcn_s_setprio(0);
  };
  auto epi = [&](const f32x4* acc) {
    #pragma unroll
    for (int m = 0; m < 2; ++m) {
      const float mx = fmaxf(fmaxf(acc[m][0], acc[m][1]),
                             fmaxf(acc[m][2], acc[m][3]));
      if (__any(mx > C0)) {
        #pragma unroll
        for (int e = 0; e < 4; ++e) {
          const float c = acc[m][e];
          const float s2 = fmaxf(fmaf(-c, c, 1.0f), 0.0f);
          const float sn = __builtin_amdgcn_sqrtf(s2);
          float tt = fmaf(c, CA, CC);
          tt = fmaf(sn, -CB, tt);
          rsum[m][e] += __builtin_amdgcn_exp2f(tt);
        }
      }
    }
  };

  // depth-3 B-prefetch (4 named buffers) + epilogue double-pipeline
  // (2 named acc sets). Invariant at loop top: aA = mfma(frag nn),
  // b1 = frag nn+1, b2 = frag nn+2, b3 about to load frag nn+3.
  i32x8 b0, b1, b2, b3;
  f32x4 aA[2], aB[2];
  loadB(&b0, 0);
  loadB(&b1, 1);
  loadB(&b2, 2);
  mfmaStep(b0, aA);
  for (int nn = 0; nn < 48; nn += 4) {
    loadB(&b3, nn + 3);                   mfmaStep(b1, aB);  epi(aA);  // frag nn
    if (nn + 4 < 50) loadB(&b0, nn + 4);  mfmaStep(b2, aA);  epi(aB);  // frag nn+1
    if (nn + 5 < 50) loadB(&b1, nn + 5);  mfmaStep(b3, aB);  epi(aA);  // frag nn+2
    if (nn + 6 < 50) loadB(&b2, nn + 6);  mfmaStep(b0, aA);  epi(aB);  // frag nn+3
  }
  // exit state: aA = mfma(frag 48), b1 = frag 49
  mfmaStep(b1, aB);
  epi(aA);                                // frag 48
  epi(aB);                                // frag 49

  // reduce over the 16 class-lanes, then one atomic per row
  #pragma unroll
  for (int m = 0; m < 2; ++m)
    #pragma unroll
    for (int e = 0; e < 4; ++e) {
      float v = rsum[m][e];
      #pragma unroll
      for (int off = 1; off < 16; off <<= 1) v += __shfl_xor(v, off, 64);
      if (r == 0)
        atomicAdd(&rowsum[rowbase + 16 * m + 4 * q + e], v);
    }
}

// ---- finalize: target-term swap, log, mean ----
__global__ void __launch_bounds__(256) k_final(const float* __restrict__ rowsum,
                                               const float2* __restrict__ cost,
                                               float* __restrict__ out) {
  __shared__ float red[256];
  float part = 0.f;
  for (int b = threadIdx.x; b < NB; b += 256) {
    const float2 cb = cost[b];
    const float ce = fminf(cb.x, 1.0f);                       // exact cos (clip)
    const float cq = cb.y;                                    // fp8-replica cos
    const float s2 = fmaxf(fmaf(-cq, cq, 1.0f), 0.0f);
    const float sn = __builtin_amdgcn_sqrtf(s2);
    float tt = fmaf(cq, CA, CC);
    tt = fmaf(sn, -CB, tt);
    // k_main's add for the target column: fires iff its m-group max > C0;
    // group-max >= cq, and when cq <= C0 the term is <=5e-37 (negligible
    // vs rowsum ~2^-105), so replicating with (cq > C0) matches.
    const float v_ctm = (cq > C0) ? __builtin_amdgcn_exp2f(tt) : 0.0f;
    const float logit_t = SCALE * (ce - MM);                  // true target logit
    const float v_tgt = __builtin_amdgcn_exp2f((logit_t - SCALE) * LOG2E);
    float sum = rowsum[b] - v_ctm + v_tgt;
    sum = fmaxf(sum, 1e-37f);
    part += __builtin_amdgcn_logf(sum) * 0.6931471805599453f + SCALE - logit_t;
  }
  red[threadIdx.x] = part;
  __syncthreads();
  #pragma unroll
  for (int s = 128; s > 0; s >>= 1) {
    if (threadIdx.x < s) red[threadIdx.x] += red[threadIdx.x + s];
    __syncthreads();
  }
  if (threadIdx.x == 0) out[0] = red[0] * (1.0f / NB);
}

extern "C" void kernel_launch(void* const* d_in, const int* in_sizes, int n_in,
                              void* d_out, int out_size, void* d_ws, size_t ws_size,
                              hipStream_t stream) {
  const float* x   = (const float*)d_in[0];
  const int*   tgt = (const int*)d_in[1];
  const float* w   = (const float*)d_in[2];
  float* out = (float*)d_out;

  char* ws = (char*)d_ws;
  const size_t WN_B = (size_t)NCP * 128;       // 13,107,200
  const size_t XN_B = (size_t)NB * 128;        // 262,144
  uint32_t* wn32   = (uint32_t*)ws;
  uint32_t* xn32   = (uint32_t*)(ws + WN_B);
  float2*   cost   = (float2*)(ws + WN_B + XN_B);
  float*    rowsum = (float*)(ws + WN_B + XN_B + NB * 8);
  if (ws_size < WN_B + XN_B + (size_t)NB * 12) return;

  k_norm <<<13056, 256, 0, stream>>>(x, w, xn32, wn32, rowsum);
  k_tdot <<<512,   256, 0, stream>>>(x, w, xn32, wn32, tgt, cost);
  k_main <<<2048,  256, 0, stream>>>(xn32, wn32, rowsum);
  k_final<<<1,     256, 0, stream>>>(rowsum, cost, out);
}

// Round 24
// 57.829 us; speedup vs baseline: 1.3708x; 1.0376x over previous
//
#include <hip/hip_runtime.h>
#include <stdint.h>

typedef float f32x4 __attribute__((ext_vector_type(4)));
typedef int   i32x8 __attribute__((ext_vector_type(8)));

// ArcFace constants (margin=0.5, scale=70)
constexpr float COS_M = 0.8775825618903728f;
constexpr float SIN_M = 0.4794255386042030f;
constexpr float MM    = 0.2397127693021015f;   // sin(pi-0.5)*0.5
constexpr float SCALE = 70.0f;
constexpr float LOG2E = 1.4426950408889634f;
constexpr float CA =  SCALE * COS_M * LOG2E;   // coeff on cos
constexpr float CB =  SCALE * SIN_M * LOG2E;   // coeff on sin
constexpr float CC = -SCALE * LOG2E;           // -70 shift, log2 domain

// skip threshold: c < 0.30 -> tt < -120.6 (log2); measured absmax 0.0625
// (threshold 0.2) across R5-R23, deterministic. Per-m 4-value gate.
constexpr float C0 = 0.30f;
constexpr int SCL1 = 0x7f7f7f7f;               // E8M0 127 = 1.0 per 32-block

constexpr int NB = 2048, NC = 100000, ND = 128;
constexpr int NCP = 102400;                    // padded classes = 128 cg x 800
// k_main: R19/R22 structure (2048 blocks = 16 rb x 128 cg, 8 waves/SIMD,
// zero LDS/barriers, B fragment-major L2-resident, mfma_scale K=128,
// depth-3 B-prefetch, T15 acc double-pipeline). tdot folded into k_norm
// as a third block-range, replicating the fp8 quantization bitwise.

// scaled-K128 fragment-major dword index for dword d (0..31) of class-col c
__device__ __forceinline__ uint32_t widx(int c, int d) {
  return (uint32_t)((c >> 4) * 512 + (d >> 3) * 128 + (c & 15) * 8 + (d & 7));
}

// ---- fused normalize + target-cos ----
// blocks [0,12800): w rows (8/block) -> wn32 (frag-major fp8)
// blocks [12800,13056): x rows (8/block) -> xn32 (linear fp8); rowsum zero
// blocks [13056,13312): target-cos (8 rows/block), quantization REPLICATED
//   bitwise (same float4 read, same 5-step half-wave reduce, same cvt_pk).
__global__ void __launch_bounds__(256) k_norm(const float* __restrict__ x,
                                              const float* __restrict__ w,
                                              const int* __restrict__ tgt,
                                              uint32_t* __restrict__ xn32,
                                              uint32_t* __restrict__ wn32,
                                              float* __restrict__ rowsum,
                                              float2* __restrict__ cost) {
  const int wv = threadIdx.x >> 6, lane = threadIdx.x & 63;
  const int h = lane >> 5, j = lane & 31;
  if (blockIdx.x < 12800) {
    const int c = blockIdx.x * 8 + wv * 2 + h;
    if (c >= NC) { wn32[widx(c, j)] = 0u; return; }
    const float4 f = reinterpret_cast<const float4*>(w + (size_t)c * ND)[j];
    float ss = f.x * f.x + f.y * f.y + f.z * f.z + f.w * f.w;
    #pragma unroll
    for (int off = 1; off < 32; off <<= 1) ss += __shfl_xor(ss, off, 64);
    const float sc = __builtin_amdgcn_rsqf(fmaxf(ss, 1e-24f));
    int pk = __builtin_amdgcn_cvt_pk_fp8_f32(f.x * sc, f.y * sc, 0, false);
    pk = __builtin_amdgcn_cvt_pk_fp8_f32(f.z * sc, f.w * sc, pk, true);
    wn32[widx(c, j)] = (uint32_t)pk;
  } else if (blockIdx.x < 13056) {
    const int bx = blockIdx.x - 12800;                  // 0..255
    if (bx < 8) rowsum[bx * 256 + threadIdx.x] = 0.0f;
    const int row = bx * 8 + wv * 2 + h;
    const float4 f = reinterpret_cast<const float4*>(x + (size_t)row * ND)[j];
    float ss = f.x * f.x + f.y * f.y + f.z * f.z + f.w * f.w;
    #pragma unroll
    for (int off = 1; off < 32; off <<= 1) ss += __shfl_xor(ss, off, 64);
    const float sc = __builtin_amdgcn_rsqf(fmaxf(ss, 1e-24f));
    int pk = __builtin_amdgcn_cvt_pk_fp8_f32(f.x * sc, f.y * sc, 0, false);
    pk = __builtin_amdgcn_cvt_pk_fp8_f32(f.z * sc, f.w * sc, pk, true);
    xn32[row * 32 + j] = (uint32_t)pk;
  } else {
    const int b = (blockIdx.x - 13056) * 8 + wv * 2 + h;  // 0..2047
    const int t = tgt[b];
    const float4 fx = reinterpret_cast<const float4*>(x + (size_t)b * ND)[j];
    const float4 fw = reinterpret_cast<const float4*>(w + (size_t)t * ND)[j];
    float ssx = fx.x * fx.x + fx.y * fx.y + fx.z * fx.z + fx.w * fx.w;
    float ssw = fw.x * fw.x + fw.y * fw.y + fw.z * fw.z + fw.w * fw.w;
    float dot = fx.x * fw.x + fx.y * fw.y + fx.z * fw.z + fx.w * fw.w;
    #pragma unroll
    for (int off = 1; off < 32; off <<= 1) {
      ssx += __shfl_xor(ssx, off, 64);
      ssw += __shfl_xor(ssw, off, 64);
      dot += __shfl_xor(dot, off, 64);
    }
    // replicate quantization bitwise (same ops as the norm branches)
    const float scx = __builtin_amdgcn_rsqf(fmaxf(ssx, 1e-24f));
    const float scw = __builtin_amdgcn_rsqf(fmaxf(ssw, 1e-24f));
    int pkx = __builtin_amdgcn_cvt_pk_fp8_f32(fx.x * scx, fx.y * scx, 0, false);
    pkx = __builtin_amdgcn_cvt_pk_fp8_f32(fx.z * scx, fx.w * scx, pkx, true);
    int pkw = __builtin_amdgcn_cvt_pk_fp8_f32(fw.x * scw, fw.y * scw, 0, false);
    pkw = __builtin_amdgcn_cvt_pk_fp8_f32(fw.z * scw, fw.w * scw, pkw, true);
    float dq = 0.0f;
    dq += __builtin_amdgcn_cvt_f32_fp8(pkx, 0) * __builtin_amdgcn_cvt_f32_fp8(pkw, 0);
    dq += __builtin_amdgcn_cvt_f32_fp8(pkx, 1) * __builtin_amdgcn_cvt_f32_fp8(pkw, 1);
    dq += __builtin_amdgcn_cvt_f32_fp8(pkx, 2) * __builtin_amdgcn_cvt_f32_fp8(pkw, 2);
    dq += __builtin_amdgcn_cvt_f32_fp8(pkx, 3) * __builtin_amdgcn_cvt_f32_fp8(pkw, 3);
    #pragma unroll
    for (int off = 1; off < 32; off <<= 1) dq += __shfl_xor(dq, off, 64);
    if (j == 0) {
      const float de = dot / (sqrtf(ssx) * sqrtf(ssw));
      cost[b] = make_float2(de, dq);
    }
  }
}

// ---- main fused GEMM (MX-scaled fp8 K=128, global->VGPR B, no LDS/barriers) ----
__global__ void __launch_bounds__(256, 4) k_main(const uint32_t* __restrict__ xn32,
                                                 const uint32_t* __restrict__ wn32,
                                                 float* __restrict__ rowsum) {
  const int wv = threadIdx.x >> 6, lane = threadIdx.x & 63;
  const int q = lane >> 4, r = lane & 15;
  // XCD-affine: xcd = b&7 owns cgs [16*xcd, 16*xcd+16)  (1.6MB/XCD L2-resident)
  const int xcd = blockIdx.x & 7, idx = blockIdx.x >> 3;  // idx 0..255
  const int cg = xcd * 16 + (idx >> 4);                 // 0..127
  const int rb = idx & 15;                              // 0..15
  const int rowbase = rb * 128 + wv * 32;
  const int fragbase = cg * 50;                         // 50 16-col frags per cg

  // A fragments: m=2 x (16 rows); direct i32x8 deref -> 2x dwordx4, no movs
  i32x8 afrag[2];
  #pragma unroll
  for (int m = 0; m < 2; ++m)
    afrag[m] = *reinterpret_cast<const i32x8*>(
        xn32 + (size_t)(rowbase + 16 * m + r) * 32 + q * 8);

  float rsum[2][4] = {{0.f,0.f,0.f,0.f},{0.f,0.f,0.f,0.f}};

  auto loadB = [&](i32x8* buf, int nn) {
    *buf = *reinterpret_cast<const i32x8*>(
        wn32 + (size_t)(fragbase + nn) * 512 + q * 128 + r * 8);
  };
  auto mfmaStep = [&](const i32x8& buf, f32x4* acc) {
    __builtin_amdgcn_s_setprio(1);
    #pragma unroll
    for (int m = 0; m < 2; ++m)
      acc[m] = __builtin_amdgcn_mfma_scale_f32_16x16x128_f8f6f4(
          afrag[m], buf, (f32x4){0.f, 0.f, 0.f, 0.f},
          0 /*A=fp8*/, 0 /*B=fp8*/, 0, SCL1, 0, SCL1);
    __builtin_amdgcn_s_setprio(0);
  };
  auto epi = [&](const f32x4* acc) {
    #pragma unroll
    for (int m = 0; m < 2; ++m) {
      const float mx = fmaxf(fmaxf(acc[m][0], acc[m][1]),
                             fmaxf(acc[m][2], acc[m][3]));
      if (__any(mx > C0)) {
        #pragma unroll
        for (int e = 0; e < 4; ++e) {
          const float c = acc[m][e];
          const float s2 = fmaxf(fmaf(-c, c, 1.0f), 0.0f);
          const float sn = __builtin_amdgcn_sqrtf(s2);
          float tt = fmaf(c, CA, CC);
          tt = fmaf(sn, -CB, tt);
          rsum[m][e] += __builtin_amdgcn_exp2f(tt);
        }
      }
    }
  };

  // depth-3 B-prefetch (4 named buffers) + epilogue double-pipeline
  // (2 named acc sets). Invariant at loop top: aA = mfma(frag nn),
  // b1 = frag nn+1, b2 = frag nn+2, b3 about to load frag nn+3.
  i32x8 b0, b1, b2, b3;
  f32x4 aA[2], aB[2];
  loadB(&b0, 0);
  loadB(&b1, 1);
  loadB(&b2, 2);
  mfmaStep(b0, aA);
  for (int nn = 0; nn < 48; nn += 4) {
    loadB(&b3, nn + 3);                   mfmaStep(b1, aB);  epi(aA);  // frag nn
    if (nn + 4 < 50) loadB(&b0, nn + 4);  mfmaStep(b2, aA);  epi(aB);  // frag nn+1
    if (nn + 5 < 50) loadB(&b1, nn + 5);  mfmaStep(b3, aB);  epi(aA);  // frag nn+2
    if (nn + 6 < 50) loadB(&b2, nn + 6);  mfmaStep(b0, aA);  epi(aB);  // frag nn+3
  }
  // exit state: aA = mfma(frag 48), b1 = frag 49
  mfmaStep(b1, aB);
  epi(aA);                                // frag 48
  epi(aB);                                // frag 49

  // reduce over the 16 class-lanes, then one atomic per row
  #pragma unroll
  for (int m = 0; m < 2; ++m)
    #pragma unroll
    for (int e = 0; e < 4; ++e) {
      float v = rsum[m][e];
      #pragma unroll
      for (int off = 1; off < 16; off <<= 1) v += __shfl_xor(v, off, 64);
      if (r == 0)
        atomicAdd(&rowsum[rowbase + 16 * m + 4 * q + e], v);
    }
}

// ---- finalize: target-term swap, log, mean ----
__global__ void __launch_bounds__(256) k_final(const float* __restrict__ rowsum,
                                               const float2* __restrict__ cost,
                                               float* __restrict__ out) {
  __shared__ float red[256];
  float part = 0.f;
  for (int b = threadIdx.x; b < NB; b += 256) {
    const float2 cb = cost[b];
    const float ce = fminf(cb.x, 1.0f);                       // exact cos (clip)
    const float cq = cb.y;                                    // fp8-replica cos
    const float s2 = fmaxf(fmaf(-cq, cq, 1.0f), 0.0f);
    const float sn = __builtin_amdgcn_sqrtf(s2);
    float tt = fmaf(cq, CA, CC);
    tt = fmaf(sn, -CB, tt);
    // k_main's add for the target column: fires iff its m-group max > C0;
    // group-max >= cq, and when cq <= C0 the term is <=5e-37 (negligible
    // vs rowsum ~2^-105), so replicating with (cq > C0) matches.
    const float v_ctm = (cq > C0) ? __builtin_amdgcn_exp2f(tt) : 0.0f;
    const float logit_t = SCALE * (ce - MM);                  // true target logit
    const float v_tgt = __builtin_amdgcn_exp2f((logit_t - SCALE) * LOG2E);
    float sum = rowsum[b] - v_ctm + v_tgt;
    sum = fmaxf(sum, 1e-37f);
    part += __builtin_amdgcn_logf(sum) * 0.6931471805599453f + SCALE - logit_t;
  }
  red[threadIdx.x] = part;
  __syncthreads();
  #pragma unroll
  for (int s = 128; s > 0; s >>= 1) {
    if (threadIdx.x < s) red[threadIdx.x] += red[threadIdx.x + s];
    __syncthreads();
  }
  if (threadIdx.x == 0) out[0] = red[0] * (1.0f / NB);
}

extern "C" void kernel_launch(void* const* d_in, const int* in_sizes, int n_in,
                              void* d_out, int out_size, void* d_ws, size_t ws_size,
                              hipStream_t stream) {
  const float* x   = (const float*)d_in[0];
  const int*   tgt = (const int*)d_in[1];
  const float* w   = (const float*)d_in[2];
  float* out = (float*)d_out;

  char* ws = (char*)d_ws;
  const size_t WN_B = (size_t)NCP * 128;       // 13,107,200
  const size_t XN_B = (size_t)NB * 128;        // 262,144
  uint32_t* wn32   = (uint32_t*)ws;
  uint32_t* xn32   = (uint32_t*)(ws + WN_B);
  float2*   cost   = (float2*)(ws + WN_B + XN_B);
  float*    rowsum = (float*)(ws + WN_B + XN_B + NB * 8);
  if (ws_size < WN_B + XN_B + (size_t)NB * 12) return;

  k_norm <<<13312, 256, 0, stream>>>(x, w, tgt, xn32, wn32, rowsum, cost);
  k_main <<<2048,  256, 0, stream>>>(xn32, wn32, rowsum);
  k_final<<<1,     256, 0, stream>>>(rowsum, cost, out);
}